// Round 11
// baseline (231.336 us; speedup 1.0000x reference)
//
#include <hip/hip_runtime.h>
#include <cstdint>
#include <cstddef>

typedef unsigned short u16;
typedef __attribute__((ext_vector_type(8))) short bf16x8;   // 8 bf16 (4 VGPR) MFMA frag
typedef __attribute__((ext_vector_type(8))) u16   u16x8;
typedef __attribute__((ext_vector_type(4))) u16   u16x4;
typedef __attribute__((ext_vector_type(4))) short short4v;
typedef __attribute__((ext_vector_type(4))) float f32x4;
typedef __attribute__((ext_vector_type(16))) float f32x16;
typedef __attribute__((ext_vector_type(4))) unsigned int u32x4;

#define DEVI static __device__ __forceinline__

constexpr int B_   = 2;
constexpr int S_   = 2048;
constexpr int HID_ = 2048;
constexpr int NH_  = 16;
constexpr int NKV_ = 4;
constexpr int HD_  = 128;
constexpr int TOK  = B_ * S_;              // 4096
constexpr int OQKV = (NH_ + 2*NKV_) * HD_; // 3072

DEVI u16 f2bf(float f) {                  // RNE f32->bf16 (finite inputs)
  uint32_t u = __builtin_bit_cast(uint32_t, f);
  return (u16)((u + 0x7fffu + ((u >> 16) & 1u)) >> 16);
}
DEVI float bf2f(u16 h) { return __builtin_bit_cast(float, (uint32_t)h << 16); }

DEVI void gll16(const void* g, void* l) { // 16B global -> LDS direct
  __builtin_amdgcn_global_load_lds(
      (const __attribute__((address_space(1))) uint32_t*)g,
      (__attribute__((address_space(3))) uint32_t*)l, 16, 0, 0);
}

// ---------------- f32 -> bf16 convert, 3 buffers in one launch ------------
__global__ __launch_bounds__(256) void cvt3_kernel(
    const float* __restrict__ i0, u16* __restrict__ o0, int n0,
    const float* __restrict__ i1, u16* __restrict__ o1, int n1,
    const float* __restrict__ i2, u16* __restrict__ o2, int n2) {
  int idx = blockIdx.x * 256 + threadIdx.x;
  int stride = gridDim.x * 256;
#pragma unroll 1
  for (int pass = 0; pass < 3; ++pass) {
    const float* in = pass == 0 ? i0 : pass == 1 ? i1 : i2;
    u16* out       = pass == 0 ? o0 : pass == 1 ? o1 : o2;
    int n8         = pass == 0 ? n0 : pass == 1 ? n1 : n2;
    for (int i = idx; i < n8; i += stride) {
      const float4* p = reinterpret_cast<const float4*>(in) + (size_t)i * 2;
      float4 a = p[0], b = p[1];
      u16x8 v;
      v[0] = f2bf(a.x); v[1] = f2bf(a.y); v[2] = f2bf(a.z); v[3] = f2bf(a.w);
      v[4] = f2bf(b.x); v[5] = f2bf(b.y); v[6] = f2bf(b.z); v[7] = f2bf(b.w);
      reinterpret_cast<u16x8*>(out)[i] = v;
    }
  }
}

// ---------------- C[m,n] = sum_k A[m,k] * B[n,k]  (both row-major, bf16) ---
template <bool OUT_BF16>
__global__ __launch_bounds__(256) void gemm_bt_kernel(
    const u16* __restrict__ A, const u16* __restrict__ B, void* __restrict__ Cv,
    int M, int N, int K) {
  constexpr int BM = 128, BN = 128, BK = 32;
  __shared__ __align__(16) u16 As[2][BM * BK];
  __shared__ __align__(16) u16 Bs[2][BN * BK];
  const int tid  = threadIdx.x;
  const int lane = tid & 63;
  const int wid  = tid >> 6;
  const int bm = blockIdx.x * BM;
  const int bn = blockIdx.y * BN;
  const int wm = (wid >> 1) * 64;
  const int wn = (wid & 1) * 64;
  const int fr = lane & 15, fg = lane >> 4;

  const f32x4 fzero = {0.f, 0.f, 0.f, 0.f};
  f32x4 acc[4][4];
#pragma unroll
  for (int m = 0; m < 4; m++)
#pragma unroll
    for (int n = 0; n < 4; n++) acc[m][n] = fzero;

  auto stage = [&](int buf, int k0) {
#pragma unroll
    for (int i = 0; i < 2; i++) {
      int e = i * 256 + tid;  // 8-elem group: row e>>2, col (e&3)*8
      gll16(A + (size_t)(bm + (e >> 2)) * K + (k0 + (e & 3) * 8), &As[buf][e * 8]);
    }
#pragma unroll
    for (int i = 0; i < 2; i++) {
      int e = i * 256 + tid;
      gll16(B + (size_t)(bn + (e >> 2)) * K + (k0 + (e & 3) * 8), &Bs[buf][e * 8]);
    }
  };

  stage(0, 0);
  __syncthreads();
  const int nt = K / BK;
  for (int t = 0; t < nt; ++t) {
    int cur = t & 1;
    if (t + 1 < nt) stage(cur ^ 1, (t + 1) * BK);
    bf16x8 af[4], bfv[4];
#pragma unroll
    for (int m = 0; m < 4; m++)
      af[m] = *reinterpret_cast<const bf16x8*>(&As[cur][(wm + m * 16 + fr) * BK + fg * 8]);
#pragma unroll
    for (int n = 0; n < 4; n++)
      bfv[n] = *reinterpret_cast<const bf16x8*>(&Bs[cur][(wn + n * 16 + fr) * BK + fg * 8]);
#pragma unroll
    for (int m = 0; m < 4; m++)
#pragma unroll
      for (int n = 0; n < 4; n++)
        acc[m][n] = __builtin_amdgcn_mfma_f32_16x16x32_bf16(af[m], bfv[n], acc[m][n], 0, 0, 0);
    __syncthreads();
  }

#pragma unroll
  for (int m = 0; m < 4; m++)
#pragma unroll
    for (int n = 0; n < 4; n++)
#pragma unroll
      for (int j = 0; j < 4; j++) {
        size_t row = bm + wm + m * 16 + fg * 4 + j;
        size_t col = bn + wn + n * 16 + fr;
        if constexpr (OUT_BF16)
          reinterpret_cast<u16*>(Cv)[row * N + col] = f2bf(acc[m][n][j]);
        else
          reinterpret_cast<float*>(Cv)[row * N + col] = acc[m][n][j];
      }
}

// ---------------- fused RMSNorm + RoPE; one wave per (token, head-slot) ----
// Q rows are additionally scaled by 1/sqrt(128)*log2(e) so attention's
// softmax is a bare exp2.
__global__ __launch_bounds__(256) void rmsrope_kernel(
    const u16* __restrict__ qkv, const float* __restrict__ cosb,
    const float* __restrict__ sinb, const float* __restrict__ qw,
    const float* __restrict__ kw, u16* __restrict__ Q, u16* __restrict__ K) {
  int gw   = blockIdx.x * 4 + (threadIdx.x >> 6);
  int lane = threadIdx.x & 63;
  int tok  = gw / 20;
  int slot = gw - tok * 20;
  if (tok >= TOK) return;
  int b = tok >> 11, s = tok & (S_ - 1);
  const u16* src = qkv + (size_t)tok * OQKV + slot * HD_;
  float x0 = bf2f(src[lane]);
  float x1 = bf2f(src[lane + 64]);
  float ss = x0 * x0 + x1 * x1;
#pragma unroll
  for (int m = 1; m < 64; m <<= 1) ss += __shfl_xor(ss, m, 64);
  float r = rsqrtf(ss * (1.0f / 128.0f) + 1e-6f);
  const float* w = (slot < 16) ? qw : kw;
  x0 *= r * w[lane];
  x1 *= r * w[lane + 64];
  float c  = cosb[(size_t)tok * 64 + lane];
  float sn = sinb[(size_t)tok * 64 + lane];
  float partner = __shfl_xor(x0, 32, 64);
  float rot = (lane < 32) ? -partner : partner;
  x0 = x0 * c + rot * sn;
  const float QSC = 0.12751743f;  // (1/sqrt(128)) * log2(e)
  u16* dst;
  if (slot < 16) {
    x0 *= QSC; x1 *= QSC;
    dst = Q + (((size_t)b * NH_ + slot) * S_ + s) * HD_;
  } else {
    dst = K + (((size_t)b * NKV_ + (slot - 16)) * S_ + s) * HD_;
  }
  dst[lane]      = f2bf(x0);
  dst[lane + 64] = f2bf(x1);
}

// ---------------- flash attention v8: v7 + balanced V staging + permlane --
// 8 waves x 32 q-rows, KVBLK=64, double-buffered (verified structure).
// Changes vs v7: (a) V staging spread across all 512 threads (4kv x 4d per
// thread; v7 used only waves 0-3), (b) P cross-half exchange via
// v_permlane32_swap_b32 (8 instr, no LDS) instead of 16 ds_bpermute + 16
// selects. Mapping proof: {a,b}=swap(w[4tp],w[4tp+2]) -> a = own-lo/partner-hi
// pairs == verified shfl_xor mapping. Swapped QK^T (mfma(K,Q)); no max
// tracking (scores bounded after RMSNorm); softmax = bare exp2 (scale
// folded into Q); K via global_load_lds w/ pre-swizzled source.
__global__ __launch_bounds__(512, 2) void attn_kernel(
    const u16* __restrict__ Q, const u16* __restrict__ K,
    const u16* __restrict__ QKVb, u16* __restrict__ O) {
  __shared__ __align__(16) u16 Ks[2][64 * 128];
  __shared__ __align__(16) u16 Vt[2][128 * 64];
  __shared__ float rs_lds[8][32];
  const int tid  = threadIdx.x;
  const int lane = tid & 63, wid = tid >> 6;
  const int q32 = lane & 31, hi = lane >> 5;
  const int qt = blockIdx.x, bh = blockIdx.y;
  const int b = bh >> 4, h = bh & 15, kvh = h >> 2;

  const u16* Qrow  = Q + ((size_t)(b * NH_ + h) * S_ + qt * 256 + wid * 32 + q32) * HD_;
  const u16* Kbase = K + (size_t)(b * NKV_ + kvh) * S_ * HD_;
  const u16* Vbase = QKVb + (size_t)b * S_ * OQKV + (size_t)(NH_ + NKV_) * HD_ + (size_t)kvh * HD_;

  // Q fragments (B-operand): qf[m] = Q[q=q32][d = m*16 + hi*8 .. +8]
  bf16x8 qf[8];
#pragma unroll
  for (int m = 0; m < 8; m++)
    qf[m] = *reinterpret_cast<const bf16x8*>(Qrow + m * 16 + hi * 8);

  f32x16 acc[4];
#pragma unroll
  for (int n = 0; n < 4; n++)
#pragma unroll
    for (int r = 0; r < 16; r++) acc[n][r] = 0.f;

  float rs = 0.f;

  // --- staging helpers (512 threads, 1024 x 16B chunks per 64x128 tile) ---
  auto stageK = [&](int buf, int kt) {  // gll16 with pre-swizzled source
#pragma unroll
    for (int i = 0; i < 2; i++) {
      int e = i * 512 + tid;
      int krow = e >> 4, ci = e & 15;
      int cs = ci ^ (krow & 15);
      gll16(Kbase + ((size_t)kt * 64 + krow) * HD_ + cs * 8, &Ks[buf][e * 8]);
    }
  };
  // V transpose staging: all 512 threads; thread (kvg 0..15, dg 0..31) owns
  // kv rows kvg*4..+3 x d cols dg*4..+3.
  u16x4 vreg[4];
  auto loadV = [&](int kt) {
    int kvg = tid >> 5, dg = tid & 31;
#pragma unroll
    for (int i = 0; i < 4; i++)
      vreg[i] = *reinterpret_cast<const u16x4*>(
          Vbase + ((size_t)kt * 64 + kvg * 4 + i) * OQKV + dg * 4);
  };
  auto writeV = [&](int buf) {  // Vt[d][kv], chunk ^= (d^(d>>3))&7
    int kvg = tid >> 5, dg = tid & 31;
#pragma unroll
    for (int j = 0; j < 4; j++) {
      int d = dg * 4 + j;
      int sw = (d ^ (d >> 3)) & 7;
      int off = d * 128 + ((((kvg >> 1) ^ sw)) << 4) + ((kvg & 1) << 3);
      short4v wv = {(short)vreg[0][j], (short)vreg[1][j],
                    (short)vreg[2][j], (short)vreg[3][j]};
      *reinterpret_cast<short4v*>(reinterpret_cast<char*>(Vt[buf]) + off) = wv;
    }
  };

  stageK(0, 0);
  loadV(0);
  writeV(0);
  __syncthreads();

  const int NT = S_ / 64;  // 32
  for (int kt = 0; kt < NT; ++kt) {
    const int cur = kt & 1;
    if (kt + 1 < NT) { stageK(cur ^ 1, kt + 1); loadV(kt + 1); }

    // ---- QK^T (swapped): S[kv][q], kv = kb*32 + crow(r,hi) ----
    const u16* kbp = &Ks[cur][(size_t)q32 * 128];
    const int swz = lane & 15;
    unsigned int pa[4][4];
#pragma unroll
    for (int kb = 0; kb < 2; kb++) {
      f32x16 s;
#pragma unroll
      for (int r = 0; r < 16; r++) s[r] = 0.f;
      __builtin_amdgcn_s_setprio(1);
#pragma unroll
      for (int m = 0; m < 8; m++) {
        bf16x8 kf = *reinterpret_cast<const bf16x8*>(
            kbp + kb * 32 * 128 + ((((m * 2 + hi) ^ swz)) << 3));
        s = __builtin_amdgcn_mfma_f32_32x32x16_bf16(kf, qf[m], s, 0, 0, 0);
      }
      __builtin_amdgcn_s_setprio(0);
      float p[16];
#pragma unroll
      for (int r = 0; r < 16; r++) {
        p[r] = exp2f(s[r]);        // scale*log2e pre-folded into Q
        rs += p[r];
      }
      unsigned int w[8];
#pragma unroll
      for (int m2 = 0; m2 < 8; m2++) {
        unsigned int wv;
        asm("v_cvt_pk_bf16_f32 %0, %1, %2" : "=v"(wv) : "v"(p[2 * m2]), "v"(p[2 * m2 + 1]));
        w[m2] = wv;
      }
      // cross-half exchange: one permlane32_swap fills two A-frag words.
      // a' = [a_lo, b_lo], b' = [a_hi, b_hi]  (verified mapping == shfl_xor
      // version: hi0 lane gets own kv{0,1} / partner kv{4,5}; hi1 lane gets
      // partner kv{8,9} / own kv{12,13}).
#pragma unroll
      for (int tp = 0; tp < 2; tp++) {
        unsigned int a0 = w[4 * tp + 0], b0 = w[4 * tp + 2];
        unsigned int a1 = w[4 * tp + 1], b1 = w[4 * tp + 3];
        asm("v_permlane32_swap_b32 %0, %1" : "+v"(a0), "+v"(b0));
        asm("v_permlane32_swap_b32 %0, %1" : "+v"(a1), "+v"(b1));
        pa[kb * 2 + tp][0] = a0;
        pa[kb * 2 + tp][1] = a1;
        pa[kb * 2 + tp][2] = b0;
        pa[kb * 2 + tp][3] = b1;
      }
    }

    // ---- PV: acc[n] += P[q][kv] * V[kv][d], B-frags from transposed Vt ----
#pragma unroll
    for (int t = 0; t < 4; t++) {
      union { u32x4 u; bf16x8 h; } pf;
      pf.u = (u32x4){pa[t][0], pa[t][1], pa[t][2], pa[t][3]};
      __builtin_amdgcn_s_setprio(1);
#pragma unroll
      for (int n = 0; n < 4; n++) {
        int d = n * 32 + q32;
        int sw = (d ^ (d >> 3)) & 7;
        bf16x8 vf = *reinterpret_cast<const bf16x8*>(
            reinterpret_cast<const char*>(Vt[cur]) + d * 128 + (((t * 2 + hi) ^ sw) << 4));
        acc[n] = __builtin_amdgcn_mfma_f32_32x32x16_bf16(pf.h, vf, acc[n], 0, 0, 0);
      }
      __builtin_amdgcn_s_setprio(0);
    }

    if (kt + 1 < NT) writeV(cur ^ 1);
    __syncthreads();
  }

  // ---- epilogue: denominators + O write ----
  float rtot = rs + __shfl_xor(rs, 32, 64);
  if (lane < 32) rs_lds[wid][q32] = rtot;
  __syncthreads();
  float rinv[16];
#pragma unroll
  for (int r = 0; r < 16; r++)
    rinv[r] = 1.0f / rs_lds[wid][(r & 3) + 8 * (r >> 2) + 4 * hi];

  const int qrow0 = qt * 256 + wid * 32;
  u16* ob = O + ((size_t)b * S_ + qrow0) * HID_ + h * HD_ + q32;
#pragma unroll
  for (int n = 0; n < 4; n++)
#pragma unroll
    for (int r = 0; r < 16; r++) {
      int qr = (r & 3) + 8 * (r >> 2) + 4 * hi;
      ob[(size_t)qr * HID_ + n * 32] = f2bf(acc[n][r] * rinv[r]);
    }
}

// ---------------------------------------------------------------------------
extern "C" void kernel_launch(void* const* d_in, const int* in_sizes, int n_in,
                              void* d_out, int out_size, void* d_ws, size_t ws_size,
                              hipStream_t stream) {
  (void)in_sizes; (void)n_in; (void)out_size; (void)ws_size;
  const float* hs   = (const float*)d_in[0];
  const float* cosb = (const float*)d_in[1];
  const float* sinb = (const float*)d_in[2];
  const float* wqkv = (const float*)d_in[3];
  const float* qw   = (const float*)d_in[4];
  const float* kw   = (const float*)d_in[5];
  const float* wd   = (const float*)d_in[6];
  float* out = (float*)d_out;
  char* ws = (char*)d_ws;
  constexpr size_t MB = 1048576;
  u16* Xb    = (u16*)(ws + 0 * MB);    // 16 MB  X bf16        [4096][2048]
  u16* Wqkvb = (u16*)(ws + 16 * MB);   // 12 MB  w_qkv bf16    [3072][2048]
  u16* Wdb   = (u16*)(ws + 28 * MB);   //  8 MB  w_dense bf16  [2048][2048]
  u16* QKVb  = (u16*)(ws + 36 * MB);   // 24 MB  qkv bf16      [4096][3072]
  u16* Qb    = (u16*)(ws + 60 * MB);   // 16 MB  Q             [B][NH][S][HD]
  u16* Kb    = (u16*)(ws + 76 * MB);   //  4 MB  K             [B][NKV][S][HD]
  u16* Ob    = (u16*)(ws + 80 * MB);   // 16 MB  attn out      [B][S][NH*HD]

  cvt3_kernel<<<2048, 256, 0, stream>>>(hs, Xb, TOK * HID_ / 8,
                                        wqkv, Wqkvb, OQKV * HID_ / 8,
                                        wd, Wdb, HID_ * HID_ / 8);

  gemm_bt_kernel<true><<<dim3(TOK / 128, OQKV / 128), 256, 0, stream>>>(
      Xb, Wqkvb, QKVb, TOK, OQKV, HID_);

  rmsrope_kernel<<<TOK * 20 / 4, 256, 0, stream>>>(QKVb, cosb, sinb, qw, kw, Qb, Kb);

  attn_kernel<<<dim3(S_ / 256, B_ * NH_), 512, 0, stream>>>(Qb, Kb, QKVb, Ob);

  gemm_bt_kernel<false><<<dim3(TOK / 128, HID_ / 128), 256, 0, stream>>>(
      Ob, Wdb, out, TOK, HID_, HID_);
}

// Round 12
// 222.946 us; speedup vs baseline: 1.0376x; 1.0376x over previous
//
#include <hip/hip_runtime.h>
#include <cstdint>
#include <cstddef>

typedef unsigned short u16;
typedef __attribute__((ext_vector_type(8))) short bf16x8;   // 8 bf16 (4 VGPR) MFMA frag
typedef __attribute__((ext_vector_type(8))) u16   u16x8;
typedef __attribute__((ext_vector_type(4))) short short4v;
typedef __attribute__((ext_vector_type(4))) float f32x4;
typedef __attribute__((ext_vector_type(16))) float f32x16;
typedef __attribute__((ext_vector_type(4))) unsigned int u32x4;

#define DEVI static __device__ __forceinline__

constexpr int B_   = 2;
constexpr int S_   = 2048;
constexpr int HID_ = 2048;
constexpr int NH_  = 16;
constexpr int NKV_ = 4;
constexpr int HD_  = 128;
constexpr int TOK  = B_ * S_;              // 4096
constexpr int OQKV = (NH_ + 2*NKV_) * HD_; // 3072

DEVI u16 f2bf(float f) {                  // RNE f32->bf16 (finite inputs)
  uint32_t u = __builtin_bit_cast(uint32_t, f);
  return (u16)((u + 0x7fffu + ((u >> 16) & 1u)) >> 16);
}
DEVI float bf2f(u16 h) { return __builtin_bit_cast(float, (uint32_t)h << 16); }

DEVI void gll16(const void* g, void* l) { // 16B global -> LDS direct
  __builtin_amdgcn_global_load_lds(
      (const __attribute__((address_space(1))) uint32_t*)g,
      (__attribute__((address_space(3))) uint32_t*)l, 16, 0, 0);
}

// ---------------- f32 -> bf16 convert, 3 buffers in one launch ------------
__global__ __launch_bounds__(256) void cvt3_kernel(
    const float* __restrict__ i0, u16* __restrict__ o0, int n0,
    const float* __restrict__ i1, u16* __restrict__ o1, int n1,
    const float* __restrict__ i2, u16* __restrict__ o2, int n2) {
  int idx = blockIdx.x * 256 + threadIdx.x;
  int stride = gridDim.x * 256;
#pragma unroll 1
  for (int pass = 0; pass < 3; ++pass) {
    const float* in = pass == 0 ? i0 : pass == 1 ? i1 : i2;
    u16* out       = pass == 0 ? o0 : pass == 1 ? o1 : o2;
    int n8         = pass == 0 ? n0 : pass == 1 ? n1 : n2;
    for (int i = idx; i < n8; i += stride) {
      const float4* p = reinterpret_cast<const float4*>(in) + (size_t)i * 2;
      float4 a = p[0], b = p[1];
      u16x8 v;
      v[0] = f2bf(a.x); v[1] = f2bf(a.y); v[2] = f2bf(a.z); v[3] = f2bf(a.w);
      v[4] = f2bf(b.x); v[5] = f2bf(b.y); v[6] = f2bf(b.z); v[7] = f2bf(b.w);
      reinterpret_cast<u16x8*>(out)[i] = v;
    }
  }
}

// ---------------- C[m,n] = sum_k A[m,k] * B[n,k]  (both row-major, bf16) ---
template <bool OUT_BF16>
__global__ __launch_bounds__(256) void gemm_bt_kernel(
    const u16* __restrict__ A, const u16* __restrict__ B, void* __restrict__ Cv,
    int M, int N, int K) {
  constexpr int BM = 128, BN = 128, BK = 32;
  __shared__ __align__(16) u16 As[2][BM * BK];
  __shared__ __align__(16) u16 Bs[2][BN * BK];
  const int tid  = threadIdx.x;
  const int lane = tid & 63;
  const int wid  = tid >> 6;
  const int bm = blockIdx.x * BM;
  const int bn = blockIdx.y * BN;
  const int wm = (wid >> 1) * 64;
  const int wn = (wid & 1) * 64;
  const int fr = lane & 15, fg = lane >> 4;

  const f32x4 fzero = {0.f, 0.f, 0.f, 0.f};
  f32x4 acc[4][4];
#pragma unroll
  for (int m = 0; m < 4; m++)
#pragma unroll
    for (int n = 0; n < 4; n++) acc[m][n] = fzero;

  auto stage = [&](int buf, int k0) {
#pragma unroll
    for (int i = 0; i < 2; i++) {
      int e = i * 256 + tid;  // 8-elem group: row e>>2, col (e&3)*8
      gll16(A + (size_t)(bm + (e >> 2)) * K + (k0 + (e & 3) * 8), &As[buf][e * 8]);
    }
#pragma unroll
    for (int i = 0; i < 2; i++) {
      int e = i * 256 + tid;
      gll16(B + (size_t)(bn + (e >> 2)) * K + (k0 + (e & 3) * 8), &Bs[buf][e * 8]);
    }
  };

  stage(0, 0);
  __syncthreads();
  const int nt = K / BK;
  for (int t = 0; t < nt; ++t) {
    int cur = t & 1;
    if (t + 1 < nt) stage(cur ^ 1, (t + 1) * BK);
    bf16x8 af[4], bfv[4];
#pragma unroll
    for (int m = 0; m < 4; m++)
      af[m] = *reinterpret_cast<const bf16x8*>(&As[cur][(wm + m * 16 + fr) * BK + fg * 8]);
#pragma unroll
    for (int n = 0; n < 4; n++)
      bfv[n] = *reinterpret_cast<const bf16x8*>(&Bs[cur][(wn + n * 16 + fr) * BK + fg * 8]);
#pragma unroll
    for (int m = 0; m < 4; m++)
#pragma unroll
      for (int n = 0; n < 4; n++)
        acc[m][n] = __builtin_amdgcn_mfma_f32_16x16x32_bf16(af[m], bfv[n], acc[m][n], 0, 0, 0);
    __syncthreads();
  }

#pragma unroll
  for (int m = 0; m < 4; m++)
#pragma unroll
    for (int n = 0; n < 4; n++)
#pragma unroll
      for (int j = 0; j < 4; j++) {
        size_t row = bm + wm + m * 16 + fg * 4 + j;
        size_t col = bn + wn + n * 16 + fr;
        if constexpr (OUT_BF16)
          reinterpret_cast<u16*>(Cv)[row * N + col] = f2bf(acc[m][n][j]);
        else
          reinterpret_cast<float*>(Cv)[row * N + col] = acc[m][n][j];
      }
}

// ---------------- fused RMSNorm + RoPE; one wave per (token, head-slot) ----
// Q rows are additionally scaled by 1/sqrt(128)*log2(e) so attention's
// softmax is a bare exp2.
__global__ __launch_bounds__(256) void rmsrope_kernel(
    const u16* __restrict__ qkv, const float* __restrict__ cosb,
    const float* __restrict__ sinb, const float* __restrict__ qw,
    const float* __restrict__ kw, u16* __restrict__ Q, u16* __restrict__ K) {
  int gw   = blockIdx.x * 4 + (threadIdx.x >> 6);
  int lane = threadIdx.x & 63;
  int tok  = gw / 20;
  int slot = gw - tok * 20;
  if (tok >= TOK) return;
  int b = tok >> 11, s = tok & (S_ - 1);
  const u16* src = qkv + (size_t)tok * OQKV + slot * HD_;
  float x0 = bf2f(src[lane]);
  float x1 = bf2f(src[lane + 64]);
  float ss = x0 * x0 + x1 * x1;
#pragma unroll
  for (int m = 1; m < 64; m <<= 1) ss += __shfl_xor(ss, m, 64);
  float r = rsqrtf(ss * (1.0f / 128.0f) + 1e-6f);
  const float* w = (slot < 16) ? qw : kw;
  x0 *= r * w[lane];
  x1 *= r * w[lane + 64];
  float c  = cosb[(size_t)tok * 64 + lane];
  float sn = sinb[(size_t)tok * 64 + lane];
  float partner = __shfl_xor(x0, 32, 64);
  float rot = (lane < 32) ? -partner : partner;
  x0 = x0 * c + rot * sn;
  const float QSC = 0.12751743f;  // (1/sqrt(128)) * log2(e)
  u16* dst;
  if (slot < 16) {
    x0 *= QSC; x1 *= QSC;
    dst = Q + (((size_t)b * NH_ + slot) * S_ + s) * HD_;
  } else {
    dst = K + (((size_t)b * NKV_ + (slot - 16)) * S_ + s) * HD_;
  }
  dst[lane]      = f2bf(x0);
  dst[lane + 64] = f2bf(x1);
}

// ---------------- flash attention v9: v7 staging + XCD-grouped blocks -----
// 8 waves x 32 q-rows, KVBLK=64, double-buffered (verified structure).
// vs v8: (a) V staging reverted to v7's wide form (u16x8, waves 0-3 — v8's
// 8B/lane loads cost 3us), (b) 1-D grid 256 with XCD-grouped decode:
// hardware round-robins blockIdx%8 -> XCD, so xcd = blockIdx&7 selects the
// (b,kvh) group; all 32 blocks sharing one K/V pair land on ONE XCD and its
// L2 (working set K 0.5 + V 0.5 + Q 2 MB < 4 MB). Permlane P-exchange kept.
__global__ __launch_bounds__(512, 2) void attn_kernel(
    const u16* __restrict__ Q, const u16* __restrict__ K,
    const u16* __restrict__ QKVb, u16* __restrict__ O) {
  __shared__ __align__(16) u16 Ks[2][64 * 128];
  __shared__ __align__(16) u16 Vt[2][128 * 64];
  __shared__ float rs_lds[8][32];
  const int tid  = threadIdx.x;
  const int lane = tid & 63, wid = tid >> 6;
  const int q32 = lane & 31, hi = lane >> 5;
  // XCD-grouped decode: xcd (=blockIdx&7) -> (b,kvh); s -> (head, q-tile)
  const int i_   = blockIdx.x;
  const int xcd  = i_ & 7, s_ = i_ >> 3;
  const int b = xcd >> 2, kvh = xcd & 3;
  const int h = kvh * 4 + (s_ & 3);
  const int qt = s_ >> 2;                         // 0..7

  const u16* Qrow  = Q + ((size_t)(b * NH_ + h) * S_ + qt * 256 + wid * 32 + q32) * HD_;
  const u16* Kbase = K + (size_t)(b * NKV_ + kvh) * S_ * HD_;
  const u16* Vbase = QKVb + (size_t)b * S_ * OQKV + (size_t)(NH_ + NKV_) * HD_ + (size_t)kvh * HD_;

  // Q fragments (B-operand): qf[m] = Q[q=q32][d = m*16 + hi*8 .. +8]
  bf16x8 qf[8];
#pragma unroll
  for (int m = 0; m < 8; m++)
    qf[m] = *reinterpret_cast<const bf16x8*>(Qrow + m * 16 + hi * 8);

  f32x16 acc[4];
#pragma unroll
  for (int n = 0; n < 4; n++)
#pragma unroll
    for (int r = 0; r < 16; r++) acc[n][r] = 0.f;

  float rs = 0.f;

  // --- staging helpers (512 threads, 1024 x 16B chunks per 64x128 tile) ---
  auto stageK = [&](int buf, int kt) {  // gll16 with pre-swizzled source
#pragma unroll
    for (int i = 0; i < 2; i++) {
      int e = i * 512 + tid;
      int krow = e >> 4, ci = e & 15;
      int cs = ci ^ (krow & 15);
      gll16(Kbase + ((size_t)kt * 64 + krow) * HD_ + cs * 8, &Ks[buf][e * 8]);
    }
  };
  // V transpose staging: threads 0..255, each owns 4 kv rows x 8 d cols
  // (16B/lane loads — wide form, v7-verified).
  u16x8 vreg[4];
  auto loadV = [&](int kt) {
    if (tid < 256) {
      int kvb = tid >> 4, db = tid & 15;
#pragma unroll
      for (int i = 0; i < 4; i++)
        vreg[i] = *reinterpret_cast<const u16x8*>(
            Vbase + ((size_t)kt * 64 + kvb * 4 + i) * OQKV + db * 8);
    }
  };
  auto writeV = [&](int buf) {  // Vt[d][kv], chunk ^= (d^(d>>3))&7
    if (tid < 256) {
      int kvb = tid >> 4, db = tid & 15;
#pragma unroll
      for (int j = 0; j < 8; j++) {
        int d = db * 8 + j;
        int sw = (d ^ (d >> 3)) & 7;
        int off = d * 128 + ((((kvb >> 1) ^ sw)) << 4) + ((kvb & 1) << 3);
        short4v wv = {(short)vreg[0][j], (short)vreg[1][j],
                      (short)vreg[2][j], (short)vreg[3][j]};
        *reinterpret_cast<short4v*>(reinterpret_cast<char*>(Vt[buf]) + off) = wv;
      }
    }
  };

  stageK(0, 0);
  loadV(0);
  writeV(0);
  __syncthreads();

  const int NT = S_ / 64;  // 32
  for (int kt = 0; kt < NT; ++kt) {
    const int cur = kt & 1;
    if (kt + 1 < NT) { stageK(cur ^ 1, kt + 1); loadV(kt + 1); }

    // ---- QK^T (swapped): S[kv][q], kv = kb*32 + crow(r,hi) ----
    const u16* kbp = &Ks[cur][(size_t)q32 * 128];
    const int swz = lane & 15;
    unsigned int pa[4][4];
#pragma unroll
    for (int kb = 0; kb < 2; kb++) {
      f32x16 s;
#pragma unroll
      for (int r = 0; r < 16; r++) s[r] = 0.f;
      __builtin_amdgcn_s_setprio(1);
#pragma unroll
      for (int m = 0; m < 8; m++) {
        bf16x8 kf = *reinterpret_cast<const bf16x8*>(
            kbp + kb * 32 * 128 + ((((m * 2 + hi) ^ swz)) << 3));
        s = __builtin_amdgcn_mfma_f32_32x32x16_bf16(kf, qf[m], s, 0, 0, 0);
      }
      __builtin_amdgcn_s_setprio(0);
      float p[16];
#pragma unroll
      for (int r = 0; r < 16; r++) {
        p[r] = exp2f(s[r]);        // scale*log2e pre-folded into Q
        rs += p[r];
      }
      unsigned int w[8];
#pragma unroll
      for (int m2 = 0; m2 < 8; m2++) {
        unsigned int wv;
        asm("v_cvt_pk_bf16_f32 %0, %1, %2" : "=v"(wv) : "v"(p[2 * m2]), "v"(p[2 * m2 + 1]));
        w[m2] = wv;
      }
      // cross-half exchange: one permlane32_swap fills two A-frag words.
#pragma unroll
      for (int tp = 0; tp < 2; tp++) {
        unsigned int a0 = w[4 * tp + 0], b0 = w[4 * tp + 2];
        unsigned int a1 = w[4 * tp + 1], b1 = w[4 * tp + 3];
        asm("v_permlane32_swap_b32 %0, %1" : "+v"(a0), "+v"(b0));
        asm("v_permlane32_swap_b32 %0, %1" : "+v"(a1), "+v"(b1));
        pa[kb * 2 + tp][0] = a0;
        pa[kb * 2 + tp][1] = a1;
        pa[kb * 2 + tp][2] = b0;
        pa[kb * 2 + tp][3] = b1;
      }
    }

    // ---- PV: acc[n] += P[q][kv] * V[kv][d], B-frags from transposed Vt ----
#pragma unroll
    for (int t = 0; t < 4; t++) {
      union { u32x4 u; bf16x8 h; } pf;
      pf.u = (u32x4){pa[t][0], pa[t][1], pa[t][2], pa[t][3]};
      __builtin_amdgcn_s_setprio(1);
#pragma unroll
      for (int n = 0; n < 4; n++) {
        int d = n * 32 + q32;
        int sw = (d ^ (d >> 3)) & 7;
        bf16x8 vf = *reinterpret_cast<const bf16x8*>(
            reinterpret_cast<const char*>(Vt[cur]) + d * 128 + (((t * 2 + hi) ^ sw) << 4));
        acc[n] = __builtin_amdgcn_mfma_f32_32x32x16_bf16(pf.h, vf, acc[n], 0, 0, 0);
      }
      __builtin_amdgcn_s_setprio(0);
    }

    if (kt + 1 < NT) writeV(cur ^ 1);
    __syncthreads();
  }

  // ---- epilogue: denominators + O write ----
  float rtot = rs + __shfl_xor(rs, 32, 64);
  if (lane < 32) rs_lds[wid][q32] = rtot;
  __syncthreads();
  float rinv[16];
#pragma unroll
  for (int r = 0; r < 16; r++)
    rinv[r] = 1.0f / rs_lds[wid][(r & 3) + 8 * (r >> 2) + 4 * hi];

  const int qrow0 = qt * 256 + wid * 32;
  u16* ob = O + ((size_t)b * S_ + qrow0) * HID_ + h * HD_ + q32;
#pragma unroll
  for (int n = 0; n < 4; n++)
#pragma unroll
    for (int r = 0; r < 16; r++) {
      int qr = (r & 3) + 8 * (r >> 2) + 4 * hi;
      ob[(size_t)qr * HID_ + n * 32] = f2bf(acc[n][r] * rinv[r]);
    }
}

// ---------------------------------------------------------------------------
extern "C" void kernel_launch(void* const* d_in, const int* in_sizes, int n_in,
                              void* d_out, int out_size, void* d_ws, size_t ws_size,
                              hipStream_t stream) {
  (void)in_sizes; (void)n_in; (void)out_size; (void)ws_size;
  const float* hs   = (const float*)d_in[0];
  const float* cosb = (const float*)d_in[1];
  const float* sinb = (const float*)d_in[2];
  const float* wqkv = (const float*)d_in[3];
  const float* qw   = (const float*)d_in[4];
  const float* kw   = (const float*)d_in[5];
  const float* wd   = (const float*)d_in[6];
  float* out = (float*)d_out;
  char* ws = (char*)d_ws;
  constexpr size_t MB = 1048576;
  u16* Xb    = (u16*)(ws + 0 * MB);    // 16 MB  X bf16        [4096][2048]
  u16* Wqkvb = (u16*)(ws + 16 * MB);   // 12 MB  w_qkv bf16    [3072][2048]
  u16* Wdb   = (u16*)(ws + 28 * MB);   //  8 MB  w_dense bf16  [2048][2048]
  u16* QKVb  = (u16*)(ws + 36 * MB);   // 24 MB  qkv bf16      [4096][3072]
  u16* Qb    = (u16*)(ws + 60 * MB);   // 16 MB  Q             [B][NH][S][HD]
  u16* Kb    = (u16*)(ws + 76 * MB);   //  4 MB  K             [B][NKV][S][HD]
  u16* Ob    = (u16*)(ws + 80 * MB);   // 16 MB  attn out      [B][S][NH*HD]

  cvt3_kernel<<<2048, 256, 0, stream>>>(hs, Xb, TOK * HID_ / 8,
                                        wqkv, Wqkvb, OQKV * HID_ / 8,
                                        wd, Wdb, HID_ * HID_ / 8);

  gemm_bt_kernel<true><<<dim3(TOK / 128, OQKV / 128), 256, 0, stream>>>(
      Xb, Wqkvb, QKVb, TOK, OQKV, HID_);

  rmsrope_kernel<<<TOK * 20 / 4, 256, 0, stream>>>(QKVb, cosb, sinb, qw, kw, Qb, Kb);

  attn_kernel<<<256, 512, 0, stream>>>(Qb, Kb, QKVb, Ob);

  gemm_bt_kernel<false><<<dim3(TOK / 128, HID_ / 128), 256, 0, stream>>>(
      Ob, Wdb, out, TOK, HID_, HID_);
}